// Round 8
// baseline (65.855 us; speedup 1.0000x reference)
//
#include <hip/hip_runtime.h>

#define DEV __device__ __forceinline__
typedef float f32x2 __attribute__((ext_vector_type(2)));
typedef float f32x4 __attribute__((ext_vector_type(4)));
typedef __fp16 h16x2 __attribute__((ext_vector_type(2)));

DEV float rdlane(float v, int l) {
  return __int_as_float(__builtin_amdgcn_readlane(__float_as_int(v), l));
}
DEV f32x2 pkfma(f32x2 a, f32x2 b, f32x2 c) { return __builtin_elementwise_fma(a, b, c); }
DEV f32x2 splat(float x) { return (f32x2){x, x}; }
DEV f32x2 swap2(f32x2 v) { return __builtin_shufflevector(v, v, 1, 0); }
DEV f32x2 cmul(f32x2 P, f32x2 F) {            // complex multiply P*F
  f32x2 t = swap2(P);
  f32x2 m = {-t.x, t.y};
  return pkfma(splat(F.y), m, splat(F.x) * P);
}

template <int CTRL>
DEV float dppmov(float v) {                   // pure-VALU lane move
  return __int_as_float(__builtin_amdgcn_update_dpp(
      0, __float_as_int(v), CTRL, 0xf, 0xf, true));
}
// DPP xor-mask exchange (masks 1,2,8 only)
template <int M>
DEV float xorl(float v) {
  if constexpr (M == 1)       return dppmov<0xB1>(v);   // quad_perm [1,0,3,2]
  else if constexpr (M == 2)  return dppmov<0x4E>(v);   // quad_perm [2,3,0,1]
  else /* M == 8 */           return dppmov<0x128>(v);  // row_ror:8
}
// ds_swizzle xor exchange on a packed dword (masks 4,16)
template <int M>
DEV unsigned swzu(unsigned v) {
  return (unsigned)__builtin_amdgcn_ds_swizzle((int)v, M == 4 ? 0x101F : 0x401F);
}
// f16 pack/unpack: halve DS payload for exchanges
DEV unsigned pack16(float a, float b) {
  union { h16x2 h; unsigned u; } cv;
  cv.h = __builtin_amdgcn_cvt_pkrtz(a, b);
  return cv.u;
}
DEV f32x2 unpack16(unsigned u) {
  union { unsigned u; h16x2 h; } cv;
  cv.u = u;
  return (f32x2){(float)cv.h.x, (float)cv.h.y};
}

// Controlled rotation, target on LANE bit M. c1/s1 pre-masked by control
// (inactive lanes: c1=1, s1=0 -> exact identity, f16 partner error is nulled).
template <int M, bool CRX, int R0, int RS>
DEV void gate_lane(f32x2 amp[8], int lane, float c1, float s1) {
  const f32x2 C2 = splat(c1);
  if constexpr (M == 4 || M == 16) {
    // single-dword f16-packed exchange (DS pipe is the CU-shared bottleneck)
    if constexpr (CRX) {
      const f32x2 S2 = {s1, -s1};
#pragma unroll
      for (int r = R0; r < 8; r += RS) {
        f32x2 p = unpack16(swzu<M>(pack16(amp[r].y, amp[r].x))); // (p.im,p.re)
        amp[r] = pkfma(S2, p, C2 * amp[r]);
      }
    } else {
      const float sp = (lane & M) ? s1 : -s1;
      const f32x2 SP = splat(sp);
#pragma unroll
      for (int r = R0; r < 8; r += RS) {
        f32x2 p = unpack16(swzu<M>(pack16(amp[r].x, amp[r].y)));
        amp[r] = pkfma(SP, p, C2 * amp[r]);
      }
    }
  } else {
    if constexpr (CRX) {
      const f32x2 S2 = {s1, -s1};
#pragma unroll
      for (int r = R0; r < 8; r += RS) {
        f32x2 p;
        p.x = xorl<M>(amp[r].y);              // (p.im, p.re): swap folded in
        p.y = xorl<M>(amp[r].x);
        amp[r] = pkfma(S2, p, C2 * amp[r]);
      }
    } else {
      const float sp = (lane & M) ? s1 : -s1;
      const f32x2 SP = splat(sp);
#pragma unroll
      for (int r = R0; r < 8; r += RS) {
        f32x2 p;
        p.x = xorl<M>(amp[r].x);
        p.y = xorl<M>(amp[r].y);
        amp[r] = pkfma(SP, p, C2 * amp[r]);
      }
    }
  }
}

// Controlled rotation, target on an r-bit: pair (I: tbit=0, J: tbit=1).
template <bool CRX>
DEV void gate_pair(f32x2& aI, f32x2& aJ, float c1, float s1) {
  const f32x2 C2 = splat(c1);
  f32x2 nI, nJ;
  if constexpr (CRX) {
    const f32x2 S2 = {s1, -s1};
    nI = pkfma(S2, swap2(aJ), C2 * aI);
    nJ = pkfma(S2, swap2(aI), C2 * aJ);
  } else {
    nI = pkfma(splat(-s1), aJ, C2 * aI);
    nJ = pkfma(splat(s1), aI, C2 * aJ);
  }
  aI = nI; aJ = nJ;
}

// One wave = TWO batch elements, one per 32-lane half (element = lane bit 5).
// Per lane: 8 complex amps (f32x2). Amp bits: lane bits 4..0 = qubits 0..4,
// r bits 2,1,0 = qubits 5,6,7.
__global__ __launch_bounds__(256, 8) void qsim_kernel(const float* __restrict__ X,
                                                      const float* __restrict__ W,
                                                      float* __restrict__ out, int bs) {
  const int lane = threadIdx.x & 63;
  const int wave = blockIdx.x * (blockDim.x >> 6) + (threadIdx.x >> 6);
  const int b0 = wave * 2;
  if (b0 >= bs) return;

  // ---- entangling weight sincos: lane g<16 holds gate g = l*8+i -> W[l*16+i] ----
  float w = W[(((lane & 15) >> 3) << 4) + (lane & 7)];
  float sw, cw;
  __sincosf(0.5f * w, &sw, &cw);

  // ---- encoding chains: lane -> element (lane>>3)&1, qubit lane&7 (16 chains) ----
  const int ce = (lane >> 3) & 1;
  const int cq = lane & 7;
  int bb = b0 + ce; bb = bb >= bs ? bs - 1 : bb;
  const float* Xrow = X + (size_t)bb * 64;
  float ang[9];
#pragma unroll
  for (int i = 0; i < 9; ++i) {
    int idx = cq * 9 + i;                 // this chain's 9 angles are contiguous
    idx = idx > 63 ? 63 : idx;            // qubit 7 has only 1 rotation
    ang[i] = Xrow[idx];
  }
  const float Hc = 0.70710678118654752440f;
  f32x2 A = {Hc, 0.f}, B = {Hc, 0.f};     // column of (rotations * H)|0>
#pragma unroll
  for (int i = 0; i < 9; ++i) {
    float s, c;
    __sincosf(0.5f * ang[i], &s, &c);
    if (i > 0) {                          // qubit-7 chain: identity after i=0
      bool dead = (cq == 7);
      c = dead ? 1.f : c;
      s = dead ? 0.f : s;
    }
    if ((i & 1) == 0) {                   // RZ
      f32x2 nA = pkfma((f32x2){s, -s}, swap2(A), splat(c) * A);
      f32x2 nB = pkfma((f32x2){-s, s}, swap2(B), splat(c) * B);
      A = nA; B = nB;
    } else {                              // RY
      f32x2 nA = pkfma(splat(-s), B, splat(c) * A);
      f32x2 nB = pkfma(splat(c), B, splat(s) * A);
      A = nA; B = nB;
    }
  }

  // publish chain results: (A,B) per (element, qubit); 256 B per wave
  __shared__ f32x4 ldsAB[4][16];
  const int wvid = (threadIdx.x >> 6) & 3;
  if (lane < 16) ldsAB[wvid][lane] = (f32x4){A.x, A.y, B.x, B.y};
  __builtin_amdgcn_wave_barrier();        // same-wave DS ordering fence

  // ---- build product-state amplitudes (my half's element) ----
  const int half = lane >> 5;
  const int base = half * 8;
  const f32x2* b2 = (const f32x2*)&ldsAB[wvid][0];  // entry 2*k = A_k, 2*k+1 = B_k
  f32x2 P = b2[(base + 0) * 2 + ((lane >> 4) & 1)];
#pragma unroll
  for (int q = 1; q <= 4; ++q)
    P = cmul(P, b2[(base + q) * 2 + ((lane >> (4 - q)) & 1)]);
  f32x4 F5 = ldsAB[wvid][base + 5];
  f32x4 F6 = ldsAB[wvid][base + 6];
  f32x4 F7 = ldsAB[wvid][base + 7];
  f32x2 A5 = {F5.x, F5.y}, B5 = {F5.z, F5.w};
  f32x2 A6 = {F6.x, F6.y}, B6 = {F6.z, F6.w};
  f32x2 A7 = {F7.x, F7.y}, B7 = {F7.z, F7.w};
  f32x2 amp[8];
  {
    f32x2 t0 = cmul(P, A5), t1 = cmul(P, B5);
    f32x2 u00 = cmul(t0, A6), u01 = cmul(t0, B6);
    f32x2 u10 = cmul(t1, A6), u11 = cmul(t1, B6);
    amp[0] = cmul(u00, A7); amp[1] = cmul(u00, B7);
    amp[2] = cmul(u01, A7); amp[3] = cmul(u01, B7);
    amp[4] = cmul(u10, A7); amp[5] = cmul(u10, B7);
    amp[6] = cmul(u11, A7); amp[7] = cmul(u11, B7);
  }

  // ---- entangling: layer 0 = CRX, layer 1 = CRY; ctrl=q_i, tgt=q_{i+1} ----
#pragma unroll
  for (int l = 0; l < 2; ++l) {
    const bool isCRX = (l == 0);
#define CS(G, CBIT) \
    const float cg = rdlane(cw, G), sg = rdlane(sw, G); \
    const bool act = (lane >> (CBIT)) & 1; \
    const float c1 = act ? cg : 1.f, s1 = act ? sg : 0.f;
    { CS(l * 8 + 0, 4)                    // ctrl q0(b4) -> tgt q1(b3): DPP ror8
      if (isCRX) gate_lane<8, true, 0, 1>(amp, lane, c1, s1);
      else       gate_lane<8, false, 0, 1>(amp, lane, c1, s1); }
    { CS(l * 8 + 1, 3)                    // ctrl q1(b3) -> tgt q2(b2): swizzle xor4 (f16-packed)
      if (isCRX) gate_lane<4, true, 0, 1>(amp, lane, c1, s1);
      else       gate_lane<4, false, 0, 1>(amp, lane, c1, s1); }
    { CS(l * 8 + 2, 2)                    // ctrl q2(b2) -> tgt q3(b1): DPP quad
      if (isCRX) gate_lane<2, true, 0, 1>(amp, lane, c1, s1);
      else       gate_lane<2, false, 0, 1>(amp, lane, c1, s1); }
    { CS(l * 8 + 3, 1)                    // ctrl q3(b1) -> tgt q4(b0): DPP quad
      if (isCRX) gate_lane<1, true, 0, 1>(amp, lane, c1, s1);
      else       gate_lane<1, false, 0, 1>(amp, lane, c1, s1); }
    { CS(l * 8 + 4, 0)                    // ctrl q4(b0) -> tgt q5(r2): pairs (r,r+4)
#pragma unroll
      for (int r = 0; r < 4; ++r) {
        if (isCRX) gate_pair<true>(amp[r], amp[r + 4], c1, s1);
        else       gate_pair<false>(amp[r], amp[r + 4], c1, s1);
      } }
    {                                     // ctrl q5(r2) -> tgt q6(r1): r in {4..7}
      const float cg = rdlane(cw, l * 8 + 5), sg = rdlane(sw, l * 8 + 5);
      if (isCRX) { gate_pair<true>(amp[4], amp[6], cg, sg);
                   gate_pair<true>(amp[5], amp[7], cg, sg); }
      else       { gate_pair<false>(amp[4], amp[6], cg, sg);
                   gate_pair<false>(amp[5], amp[7], cg, sg); }
    }
    {                                     // ctrl q6(r1) -> tgt q7(r0): r in {2,3,6,7}
      const float cg = rdlane(cw, l * 8 + 6), sg = rdlane(sw, l * 8 + 6);
      if (isCRX) { gate_pair<true>(amp[2], amp[3], cg, sg);
                   gate_pair<true>(amp[6], amp[7], cg, sg); }
      else       { gate_pair<false>(amp[2], amp[3], cg, sg);
                   gate_pair<false>(amp[6], amp[7], cg, sg); }
    }
    {                                     // ctrl q7(r0) -> tgt q0(b4): odd r, swizzle xor16 (f16)
      const float cg = rdlane(cw, l * 8 + 7), sg = rdlane(sw, l * 8 + 7);
      if (isCRX) gate_lane<16, true, 1, 2>(amp, lane, cg, sg);
      else       gate_lane<16, false, 1, 2>(amp, lane, cg, sg);
    }
#undef CS
  }

  // ---- measurement ----
  float p[8];
#pragma unroll
  for (int r = 0; r < 8; ++r) p[r] = fmaf(amp[r].x, amp[r].x, amp[r].y * amp[r].y);
  float s01 = p[0] + p[1], s23 = p[2] + p[3], s45 = p[4] + p[5], s67 = p[6] + p[7];
  float sL = s01 + s23, sH = s45 + s67;
  float wv = sL + sH;                     // WHT input -> qubits 0..4 (lane bits)
  f32x2 D = {sL - sH,                     // q5 (r bit2)
             (s01 + s45) - (s23 + s67)};  // q6 (r bit1)
  float d7 = (p[0] - p[1]) + (p[2] - p[3]) + (p[4] - p[5]) + (p[6] - p[7]); // q7

  // butterfly: DPP stages free; swizzle stages (M=4,16) f16-packed (2 DS each)
#define STAGE_DPP(K, M)                               \
  {                                                   \
    float pp = xorl<M>(wv);                           \
    wv = pp + (((lane >> K) & 1) ? -wv : wv);         \
    f32x2 pd;                                         \
    pd.x = xorl<M>(D.x);                              \
    pd.y = xorl<M>(D.y);                              \
    D = D + pd;                                       \
    d7 += xorl<M>(d7);                                \
  }
#define STAGE_SWZ(K, M)                               \
  {                                                   \
    f32x2 u1 = unpack16(swzu<M>(pack16(wv, d7)));     \
    f32x2 u2 = unpack16(swzu<M>(pack16(D.x, D.y)));   \
    wv = u1.x + (((lane >> K) & 1) ? -wv : wv);       \
    d7 += u1.y;                                       \
    D = D + u2;                                       \
  }
  STAGE_DPP(0, 1) STAGE_DPP(1, 2) STAGE_SWZ(2, 4) STAGE_DPP(3, 8) STAGE_SWZ(4, 16)
#undef STAGE_DPP
#undef STAGE_SWZ

  // ---- gather & store: each half writes its element's 8 outputs ----
  const int lpos = lane & 31;
  const int srcl = (lane & 32) + (16 >> lpos);   // q0..q4 sit in WHT lanes 16,8,4,2,1
  float g = __shfl(wv, srcl, 64);
  float val = (lpos == 5) ? D.x : (lpos == 6) ? D.y : (lpos == 7) ? d7 : g;
  const int brow = b0 + half;
  if (lpos < 8 && brow < bs) out[(size_t)brow * 8 + lpos] = val;
}

extern "C" void kernel_launch(void* const* d_in, const int* in_sizes, int n_in,
                              void* d_out, int out_size, void* d_ws, size_t ws_size,
                              hipStream_t stream) {
  const float* X = (const float*)d_in[0];   // (bs, 64) float32
  const float* W = (const float*)d_in[1];   // (2, 16) float32
  float* out = (float*)d_out;               // (bs, 8) float32
  int bs = in_sizes[0] / 64;
  int waves = (bs + 1) / 2;                 // 2 elements per wave
  const int waves_per_block = 4;
  const int threads = waves_per_block * 64;
  int blocks = (waves + waves_per_block - 1) / waves_per_block;
  hipLaunchKernelGGL(qsim_kernel, dim3(blocks), dim3(threads), 0, stream, X, W, out, bs);
}